// Round 2
// baseline (337.388 us; speedup 1.0000x reference)
//
#include <hip/hip_runtime.h>
#include <math.h>

#define D_MODEL 768
#define D_STATE 64
#define BATCH   2
#define SEQ     2048
#define M_TOTAL (BATCH * SEQ)   // 4096

#define BM 64
#define BN 64
#define BK 16

// scan chunking
#define SWAVES 8
#define CHUNK  (SEQ / SWAVES)   // 256
#define PT     32               // timesteps per reduction subtile
#define PSTRIDE 68

// ---------------- LayerNorm: one wave per row of 768 ----------------
__global__ __launch_bounds__(256) void ln_kernel(const float* __restrict__ x,
                                                 const float* __restrict__ gamma,
                                                 const float* __restrict__ beta,
                                                 float* __restrict__ xn) {
    int row  = blockIdx.x * 4 + (threadIdx.x >> 6);
    int lane = threadIdx.x & 63;
    const float* xr = x + (size_t)row * D_MODEL;
    float4 v[3];
    v[0] = *(const float4*)(xr + lane * 4);
    v[1] = *(const float4*)(xr + 256 + lane * 4);
    v[2] = *(const float4*)(xr + 512 + lane * 4);
    float s = 0.f, ss = 0.f;
#pragma unroll
    for (int i = 0; i < 3; ++i) {
        s  += v[i].x + v[i].y + v[i].z + v[i].w;
        ss += v[i].x * v[i].x + v[i].y * v[i].y + v[i].z * v[i].z + v[i].w * v[i].w;
    }
#pragma unroll
    for (int off = 1; off < 64; off <<= 1) {
        s  += __shfl_xor(s, off, 64);
        ss += __shfl_xor(ss, off, 64);
    }
    float mean = s * (1.0f / 768.0f);
    float var  = ss * (1.0f / 768.0f) - mean * mean;
    float inv  = 1.0f / sqrtf(var + 1e-5f);
    float* xo = xn + (size_t)row * D_MODEL;
#pragma unroll
    for (int i = 0; i < 3; ++i) {
        int c = i * 256 + lane * 4;
        float4 g  = *(const float4*)(gamma + c);
        float4 bb = *(const float4*)(beta + c);
        float4 o;
        o.x = (v[i].x - mean) * inv * g.x + bb.x;
        o.y = (v[i].y - mean) * inv * g.y + bb.y;
        o.z = (v[i].z - mean) * inv * g.z + bb.z;
        o.w = (v[i].w - mean) * inv * g.w + bb.w;
        *(float4*)(xo + c) = o;
    }
}

// ---------------- in_proj GEMM: u = xn @ W_in^T + b_in, written TRANSPOSED as uT[b][d][s] ----------------
__global__ __launch_bounds__(256) void gemm_in(const float* __restrict__ A,   // xn [4096,768]
                                               const float* __restrict__ W,   // W_in [768,768]
                                               const float* __restrict__ bias,
                                               float* __restrict__ uT) {      // [2][768][2048]
    __shared__ float As[BK][BM + 4];
    __shared__ float Bs[BK][BN + 4];
    int tid = threadIdx.x;
    int bm = blockIdx.x * BM;
    int bn = blockIdx.y * BN;
    int tx = tid & 15, ty = tid >> 4;
    int lrow = tid >> 2;
    int lcol = (tid & 3) << 2;
    float acc[4][4] = {};
    for (int k0 = 0; k0 < D_MODEL; k0 += BK) {
        float4 a4 = *(const float4*)(A + (size_t)(bm + lrow) * D_MODEL + k0 + lcol);
        float4 b4 = *(const float4*)(W + (size_t)(bn + lrow) * D_MODEL + k0 + lcol);
        As[lcol + 0][lrow] = a4.x; As[lcol + 1][lrow] = a4.y;
        As[lcol + 2][lrow] = a4.z; As[lcol + 3][lrow] = a4.w;
        Bs[lcol + 0][lrow] = b4.x; Bs[lcol + 1][lrow] = b4.y;
        Bs[lcol + 2][lrow] = b4.z; Bs[lcol + 3][lrow] = b4.w;
        __syncthreads();
#pragma unroll
        for (int k = 0; k < BK; ++k) {
            float4 av = *(const float4*)&As[k][ty << 2];
            float4 bv = *(const float4*)&Bs[k][tx << 2];
            float a[4] = {av.x, av.y, av.z, av.w};
            float b[4] = {bv.x, bv.y, bv.z, bv.w};
#pragma unroll
            for (int i = 0; i < 4; ++i)
#pragma unroll
                for (int j = 0; j < 4; ++j)
                    acc[i][j] = fmaf(a[i], b[j], acc[i][j]);
        }
        __syncthreads();
    }
    int m0 = bm + (ty << 2);
    int b  = m0 >> 11;       // batch
    int s  = m0 & 2047;      // seq pos
#pragma unroll
    for (int j = 0; j < 4; ++j) {
        int n = bn + (tx << 2) + j;
        float bv = bias[n];
        float4 o = make_float4(acc[0][j] + bv, acc[1][j] + bv, acc[2][j] + bv, acc[3][j] + bv);
        *(float4*)(uT + (size_t)b * D_MODEL * SEQ + (size_t)n * SEQ + s) = o;
    }
}

// ---------------- SSM scan: chunked parallel scan ----------------
// Block = 8 waves, one (b,d) channel per block. Wave w owns timesteps
// [w*256, w*256+256). lane = state index n.
// Phase 1: local recurrence h0=0 -> end state per wave (registers only).
// Phase 2: one barrier; Horner-combine predecessor end states with Ab^256.
// Phase 3: re-run from true incoming state, emit y via per-wave private
//          32x68 LDS transpose tile (no block barriers in the loop).
__global__ __launch_bounds__(512) void scan_kernel(const float* __restrict__ uT,
                                                   const float* __restrict__ log_A,
                                                   const float* __restrict__ B_p,
                                                   const float* __restrict__ C_p,
                                                   const float* __restrict__ D_p,
                                                   const float* __restrict__ log_dt,
                                                   float* __restrict__ yT) {
    int d = blockIdx.x;      // 0..767
    int b = blockIdx.y;      // 0..1
    int tid  = threadIdx.x;
    int w    = tid >> 6;     // wave id 0..7 = time chunk
    int lane = tid & 63;     // state n
    float dt = expf(log_dt[d]);
    int idx = d * 64 + lane;
    float a  = -dt * expf(log_A[idx]);   // dt*A (<= 0)
    float Ab = expf(a);
    float Bb = B_p[idx] * dt;
    float Cc = C_p[idx];
    float Dd = D_p[d];
    const float* up = uT + ((size_t)b * D_MODEL + (size_t)d) * SEQ;
    float*       yp = yT + ((size_t)b * D_MODEL + (size_t)d) * SEQ;
    const float* uw = up + w * CHUNK;

    __shared__ float Hend[SWAVES][64];
    __shared__ float P[SWAVES][PT][PSTRIDE];

    // ---- Phase 1: local scan, h0 = 0 ----
    float h = 0.f;
    for (int t0 = 0; t0 < CHUNK; t0 += 64) {
        float uc = uw[t0 + lane];           // coalesced
#pragma unroll
        for (int j = 0; j < 64; ++j) {
            float ut = __shfl(uc, j, 64);   // literal-index broadcast
            h = fmaf(Ab, h, Bb * ut);
        }
    }
    Hend[w][lane] = h;
    __syncthreads();

    // ---- Phase 2: incoming state H_w = sum_{v<w} Ab^{256*(w-1-v)} * Hend[v] ----
    float AbL = expf((float)CHUNK * a);     // Ab^256, exact via exp
    float H = 0.f;
    for (int v = 0; v < w; ++v)
        H = fmaf(H, AbL, Hend[v][lane]);

    // ---- Phase 3: true scan from H, emit y ----
    h = H;
    float* Pw = &P[w][0][0];
    for (int t0 = 0; t0 < CHUNK; t0 += 64) {
        float uc = uw[t0 + lane];
#pragma unroll
        for (int half = 0; half < 2; ++half) {
#pragma unroll
            for (int j = 0; j < 32; ++j) {
                float ut = __shfl(uc, half * 32 + j, 64);
                h = fmaf(Ab, h, Bb * ut);
                Pw[j * PSTRIDE + lane] = h * Cc;
            }
            __builtin_amdgcn_wave_barrier();   // pin write->read order (no HW cost)
            // reduce: lane l -> timestep tl = l>>1, half-sum part = l&1
            int tl = lane >> 1, part = lane & 1;
            float s = 0.f;
#pragma unroll
            for (int q = 0; q < 8; ++q) {
                float4 pv = *(const float4*)&Pw[tl * PSTRIDE + part * 32 + q * 4];
                s += (pv.x + pv.y) + (pv.z + pv.w);
            }
            s += __shfl_xor(s, 1, 64);
            float ut2 = __shfl(uc, half * 32 + tl, 64);
            if (part == 0)
                yp[w * CHUNK + t0 + half * 32 + tl] = fmaf(Dd, ut2, s);
            __builtin_amdgcn_wave_barrier();   // keep next subtile's writes after reads
        }
    }
}

// ---------------- out_proj GEMM: out = y @ W_out^T + b_out + x  (A read from transposed yT) ----------------
__global__ __launch_bounds__(256) void gemm_out(const float* __restrict__ yT,  // [2][768][2048]
                                                const float* __restrict__ W,   // W_out [768,768]
                                                const float* __restrict__ bias,
                                                const float* __restrict__ resid, // x [4096,768]
                                                float* __restrict__ out) {       // [4096,768]
    __shared__ float As[BK][BM + 4];
    __shared__ float Bs[BK][BN + 4];
    int tid = threadIdx.x;
    int bm = blockIdx.x * BM;
    int bn = blockIdx.y * BN;
    int tx = tid & 15, ty = tid >> 4;
    int lrow = tid >> 2;
    int lcol = (tid & 3) << 2;
    int drow = tid >> 4;            // 0..15 : k-row of A tile
    int scol = (tid & 15) << 2;     // 0..60 : m-col of A tile
    int b  = bm >> 11;
    int s0 = bm & 2047;
    const float* Abase = yT + (size_t)b * D_MODEL * SEQ + s0;
    float acc[4][4] = {};
    for (int k0 = 0; k0 < D_MODEL; k0 += BK) {
        float4 a4 = *(const float4*)(Abase + (size_t)(k0 + drow) * SEQ + scol);
        float4 b4 = *(const float4*)(W + (size_t)(bn + lrow) * D_MODEL + k0 + lcol);
        *(float4*)&As[drow][scol] = a4;   // already [k][m] orientation
        Bs[lcol + 0][lrow] = b4.x; Bs[lcol + 1][lrow] = b4.y;
        Bs[lcol + 2][lrow] = b4.z; Bs[lcol + 3][lrow] = b4.w;
        __syncthreads();
#pragma unroll
        for (int k = 0; k < BK; ++k) {
            float4 av = *(const float4*)&As[k][ty << 2];
            float4 bv = *(const float4*)&Bs[k][tx << 2];
            float a[4] = {av.x, av.y, av.z, av.w};
            float bb[4] = {bv.x, bv.y, bv.z, bv.w};
#pragma unroll
            for (int i = 0; i < 4; ++i)
#pragma unroll
                for (int j = 0; j < 4; ++j)
                    acc[i][j] = fmaf(a[i], bb[j], acc[i][j]);
        }
        __syncthreads();
    }
#pragma unroll
    for (int i = 0; i < 4; ++i) {
        int m  = bm + (ty << 2) + i;
        int n0 = bn + (tx << 2);
        float4 bv = *(const float4*)(bias + n0);
        float4 rv = *(const float4*)(resid + (size_t)m * D_MODEL + n0);
        float4 o = make_float4(acc[i][0] + bv.x + rv.x,
                               acc[i][1] + bv.y + rv.y,
                               acc[i][2] + bv.z + rv.z,
                               acc[i][3] + bv.w + rv.w);
        *(float4*)(out + (size_t)m * D_MODEL + n0) = o;
    }
}

extern "C" void kernel_launch(void* const* d_in, const int* in_sizes, int n_in,
                              void* d_out, int out_size, void* d_ws, size_t ws_size,
                              hipStream_t stream) {
    const float* x        = (const float*)d_in[0];
    const float* ln_gamma = (const float*)d_in[1];
    const float* ln_beta  = (const float*)d_in[2];
    const float* W_in     = (const float*)d_in[3];
    const float* b_in     = (const float*)d_in[4];
    const float* log_A    = (const float*)d_in[5];
    const float* B_p      = (const float*)d_in[6];
    const float* C_p      = (const float*)d_in[7];
    const float* D_p      = (const float*)d_in[8];
    const float* log_dt   = (const float*)d_in[9];
    const float* W_out    = (const float*)d_in[10];
    const float* b_out    = (const float*)d_in[11];
    float* out = (float*)d_out;

    float* xn = (float*)d_ws;                               // [4096,768]
    float* uT = xn + (size_t)M_TOTAL * D_MODEL;             // [2][768][2048]
    float* yT = uT + (size_t)M_TOTAL * D_MODEL;             // [2][768][2048]

    ln_kernel<<<dim3(M_TOTAL / 4), dim3(256), 0, stream>>>(x, ln_gamma, ln_beta, xn);
    gemm_in<<<dim3(M_TOTAL / BM, D_MODEL / BN), dim3(256), 0, stream>>>(xn, W_in, b_in, uT);
    scan_kernel<<<dim3(D_MODEL, BATCH), dim3(512), 0, stream>>>(uT, log_A, B_p, C_p, D_p, log_dt, yT);
    gemm_out<<<dim3(M_TOTAL / BM, D_MODEL / BN), dim3(256), 0, stream>>>(yT, W_out, b_out, x, out);
}

// Round 3
// 165.486 us; speedup vs baseline: 2.0388x; 2.0388x over previous
//
#include <hip/hip_runtime.h>
#include <math.h>

#define D_MODEL 768
#define D_STATE 64
#define BATCH   2
#define SEQ     2048
#define M_TOTAL (BATCH * SEQ)   // 4096

// scan chunking
#define SWAVES 8
#define CHUNK  (SEQ / SWAVES)   // 256
#define PT     32
#define PSTRIDE 68

typedef unsigned short ushort_t;
typedef float f32x4 __attribute__((ext_vector_type(4)));
typedef __bf16 bf16x8 __attribute__((ext_vector_type(8)));

__device__ __forceinline__ ushort_t f2bf(float f) {
    unsigned u = __float_as_uint(f);
    u = (u + 0x7FFFu + ((u >> 16) & 1u)) >> 16;   // RNE
    return (ushort_t)u;
}

__device__ __forceinline__ void gload16(const void* g, void* shm) {
    __builtin_amdgcn_global_load_lds(
        (const __attribute__((address_space(1))) void*)g,
        (__attribute__((address_space(3))) void*)shm, 16, 0, 0);
}

// ---------------- weight cast fp32 -> bf16 ----------------
__global__ __launch_bounds__(256) void cast2_kernel(const float* __restrict__ w0,
                                                    const float* __restrict__ w1,
                                                    ushort_t* __restrict__ o0,
                                                    ushort_t* __restrict__ o1) {
    const float* src = blockIdx.y ? w1 : w0;
    ushort_t*    dst = blockIdx.y ? o1 : o0;
    int i = (blockIdx.x * 256 + threadIdx.x) * 4;
    float4 v = *(const float4*)(src + i);
    ushort4 o = make_ushort4(f2bf(v.x), f2bf(v.y), f2bf(v.z), f2bf(v.w));
    *(ushort4*)(dst + i) = o;
}

// ---------------- LayerNorm -> bf16 xn ----------------
__global__ __launch_bounds__(256) void ln_kernel(const float* __restrict__ x,
                                                 const float* __restrict__ gamma,
                                                 const float* __restrict__ beta,
                                                 ushort_t* __restrict__ xnb) {
    int row  = blockIdx.x * 4 + (threadIdx.x >> 6);
    int lane = threadIdx.x & 63;
    const float* xr = x + (size_t)row * D_MODEL;
    float4 v[3];
    v[0] = *(const float4*)(xr + lane * 4);
    v[1] = *(const float4*)(xr + 256 + lane * 4);
    v[2] = *(const float4*)(xr + 512 + lane * 4);
    float s = 0.f, ss = 0.f;
#pragma unroll
    for (int i = 0; i < 3; ++i) {
        s  += v[i].x + v[i].y + v[i].z + v[i].w;
        ss += v[i].x * v[i].x + v[i].y * v[i].y + v[i].z * v[i].z + v[i].w * v[i].w;
    }
#pragma unroll
    for (int off = 1; off < 64; off <<= 1) {
        s  += __shfl_xor(s, off, 64);
        ss += __shfl_xor(ss, off, 64);
    }
    float mean = s * (1.0f / 768.0f);
    float var  = ss * (1.0f / 768.0f) - mean * mean;
    float inv  = 1.0f / sqrtf(var + 1e-5f);
    ushort_t* xo = xnb + (size_t)row * D_MODEL;
#pragma unroll
    for (int i = 0; i < 3; ++i) {
        int c = i * 256 + lane * 4;
        float4 g  = *(const float4*)(gamma + c);
        float4 bb = *(const float4*)(beta + c);
        ushort4 o = make_ushort4(f2bf((v[i].x - mean) * inv * g.x + bb.x),
                                 f2bf((v[i].y - mean) * inv * g.y + bb.y),
                                 f2bf((v[i].z - mean) * inv * g.z + bb.z),
                                 f2bf((v[i].w - mean) * inv * g.w + bb.w));
        *(ushort4*)(xo + c) = o;
    }
}

// ---------------- bf16 MFMA GEMM core macro pieces ----------------
// Tile: BM=BN=64, stage depth 64 (bf16). LDS: As/Bs 8KB each, row = 64 bf16
// = 128B, 8 segs of 16B. Seg s of row r stores elements (s ^ (r&7))*8..+7
// (XOR swizzle -> 2-way-max bank aliasing on ds_read_b128 frag reads, which
// is free, while keeping global_load_lds's lane-contiguous LDS dst).

// gemm_in: u = xn @ W_in^T + b_in, epilogue writes uT[b][n][s] fp32 via LDS transpose
__global__ __launch_bounds__(256) void gemm_in(const ushort_t* __restrict__ A,   // xn bf16 [4096][768]
                                               const ushort_t* __restrict__ B,   // W_in bf16 [768][768]
                                               const float* __restrict__ bias,
                                               float* __restrict__ uT) {
    __shared__ __align__(16) char smem[64 * 68 * 4];   // 17408B; staging uses first 16KB
    ushort_t* As = (ushort_t*)smem;
    ushort_t* Bs = (ushort_t*)(smem + 8192);
    float*    T  = (float*)smem;

    int tid = threadIdx.x;
    int w = tid >> 6, l = tid & 63;
    int bm = blockIdx.x * 64, bn = blockIdx.y * 64;
    int mq = (w & 1) * 32, nq = (w >> 1) * 32;

    int rowA = w * 8 + (l >> 3);
    int segx = ((l & 7) ^ (rowA & 7)) * 8;
    const ushort_t* gA0 = A + (size_t)(bm + rowA) * D_MODEL + segx;
    const ushort_t* gB0 = B + (size_t)(bn + rowA) * D_MODEL + segx;
    char* dA = smem + w * 1024;          // wave-uniform LDS base (lane*16 added by HW)
    char* dB = smem + 8192 + w * 1024;

    float biasv[2];
#pragma unroll
    for (int nt = 0; nt < 2; ++nt)
        biasv[nt] = bias[bn + nq + nt * 16 + (l & 15)];

    f32x4 acc[2][2] = {};
    for (int k0 = 0; k0 < D_MODEL; k0 += 64) {
        gload16(gA0 + k0, dA);
        gload16(gA0 + k0 + (size_t)32 * D_MODEL, dA + 4096);
        gload16(gB0 + k0, dB);
        gload16(gB0 + k0 + (size_t)32 * D_MODEL, dB + 4096);
        __syncthreads();
#pragma unroll
        for (int kk = 0; kk < 2; ++kk) {
            bf16x8 af[2], bf[2];
#pragma unroll
            for (int mt = 0; mt < 2; ++mt) {
                int r = mq + mt * 16 + (l & 15);
                int sgi = (kk * 4 + (l >> 4)) ^ (r & 7);
                af[mt] = *(const bf16x8*)(smem + r * 128 + sgi * 16);
            }
#pragma unroll
            for (int nt = 0; nt < 2; ++nt) {
                int r = nq + nt * 16 + (l & 15);
                int sgi = (kk * 4 + (l >> 4)) ^ (r & 7);
                bf[nt] = *(const bf16x8*)(smem + 8192 + r * 128 + sgi * 16);
            }
#pragma unroll
            for (int mt = 0; mt < 2; ++mt)
#pragma unroll
                for (int nt = 0; nt < 2; ++nt)
                    acc[mt][nt] = __builtin_amdgcn_mfma_f32_16x16x32_bf16(af[mt], bf[nt], acc[mt][nt], 0, 0, 0);
        }
        __syncthreads();
    }
    // epilogue: LDS transpose -> uT[b][n][s] coalesced
#pragma unroll
    for (int mt = 0; mt < 2; ++mt)
#pragma unroll
        for (int nt = 0; nt < 2; ++nt)
#pragma unroll
            for (int i = 0; i < 4; ++i) {
                int nl = nq + nt * 16 + (l & 15);
                int ml = mq + mt * 16 + (l >> 4) * 4 + i;
                T[nl * 68 + ml] = acc[mt][nt][i] + biasv[nt];
            }
    __syncthreads();
    int b = bm >> 11, sbase = bm & 2047;
    int n = tid >> 2, mseg = (tid & 3) * 16;
    float* dst = uT + ((size_t)b * D_MODEL + bn + n) * SEQ + sbase + mseg;
#pragma unroll
    for (int q = 0; q < 4; ++q)
        *(float4*)(dst + q * 4) = *(const float4*)&T[n * 68 + mseg + q * 4];
}

// gemm_out: out = y @ W_out^T + b_out + resid, natural [m][n] store
__global__ __launch_bounds__(256) void gemm_out(const ushort_t* __restrict__ A,   // y bf16 [4096][768]
                                                const ushort_t* __restrict__ B,   // W_out bf16 [768][768]
                                                const float* __restrict__ bias,
                                                const float* __restrict__ resid,
                                                float* __restrict__ out) {
    __shared__ __align__(16) char smem[16384];
    int tid = threadIdx.x;
    int w = tid >> 6, l = tid & 63;
    int bm = blockIdx.x * 64, bn = blockIdx.y * 64;
    int mq = (w & 1) * 32, nq = (w >> 1) * 32;

    int rowA = w * 8 + (l >> 3);
    int segx = ((l & 7) ^ (rowA & 7)) * 8;
    const ushort_t* gA0 = A + (size_t)(bm + rowA) * D_MODEL + segx;
    const ushort_t* gB0 = B + (size_t)(bn + rowA) * D_MODEL + segx;
    char* dA = smem + w * 1024;
    char* dB = smem + 8192 + w * 1024;

    float biasv[2];
#pragma unroll
    for (int nt = 0; nt < 2; ++nt)
        biasv[nt] = bias[bn + nq + nt * 16 + (l & 15)];

    f32x4 acc[2][2] = {};
    for (int k0 = 0; k0 < D_MODEL; k0 += 64) {
        gload16(gA0 + k0, dA);
        gload16(gA0 + k0 + (size_t)32 * D_MODEL, dA + 4096);
        gload16(gB0 + k0, dB);
        gload16(gB0 + k0 + (size_t)32 * D_MODEL, dB + 4096);
        __syncthreads();
#pragma unroll
        for (int kk = 0; kk < 2; ++kk) {
            bf16x8 af[2], bf[2];
#pragma unroll
            for (int mt = 0; mt < 2; ++mt) {
                int r = mq + mt * 16 + (l & 15);
                int sgi = (kk * 4 + (l >> 4)) ^ (r & 7);
                af[mt] = *(const bf16x8*)(smem + r * 128 + sgi * 16);
            }
#pragma unroll
            for (int nt = 0; nt < 2; ++nt) {
                int r = nq + nt * 16 + (l & 15);
                int sgi = (kk * 4 + (l >> 4)) ^ (r & 7);
                bf[nt] = *(const bf16x8*)(smem + 8192 + r * 128 + sgi * 16);
            }
#pragma unroll
            for (int mt = 0; mt < 2; ++mt)
#pragma unroll
                for (int nt = 0; nt < 2; ++nt)
                    acc[mt][nt] = __builtin_amdgcn_mfma_f32_16x16x32_bf16(af[mt], bf[nt], acc[mt][nt], 0, 0, 0);
        }
        __syncthreads();
    }
#pragma unroll
    for (int mt = 0; mt < 2; ++mt)
#pragma unroll
        for (int i = 0; i < 4; ++i) {
            int m = bm + mq + mt * 16 + (l >> 4) * 4 + i;
            const float* rp = resid + (size_t)m * D_MODEL + bn;
            float* op = out + (size_t)m * D_MODEL + bn;
#pragma unroll
            for (int nt = 0; nt < 2; ++nt) {
                int nl = nq + nt * 16 + (l & 15);
                op[nl] = acc[mt][nt][i] + biasv[nt] + rp[nl];
            }
        }
}

// ---------------- SSM scan: chunked parallel scan (readlane broadcasts) ----------------
__global__ __launch_bounds__(512) void scan_kernel(const float* __restrict__ uT,
                                                   const float* __restrict__ log_A,
                                                   const float* __restrict__ B_p,
                                                   const float* __restrict__ C_p,
                                                   const float* __restrict__ D_p,
                                                   const float* __restrict__ log_dt,
                                                   float* __restrict__ yT) {
    int d = blockIdx.x;
    int b = blockIdx.y;
    int tid  = threadIdx.x;
    int w    = tid >> 6;
    int lane = tid & 63;
    float dt = expf(log_dt[d]);
    int idx = d * 64 + lane;
    float a  = -dt * expf(log_A[idx]);
    float Ab = expf(a);
    float Bb = B_p[idx] * dt;
    float Cc = C_p[idx];
    float Dd = D_p[d];
    const float* up = uT + ((size_t)b * D_MODEL + (size_t)d) * SEQ;
    float*       yp = yT + ((size_t)b * D_MODEL + (size_t)d) * SEQ;
    const float* uw = up + w * CHUNK;

    __shared__ float Hend[SWAVES][64];
    __shared__ float P[SWAVES][PT][PSTRIDE];

    // Phase 1: local scan, h0 = 0 (pure VALU: v_readlane broadcasts)
    float h = 0.f;
    for (int t0 = 0; t0 < CHUNK; t0 += 64) {
        float uc = uw[t0 + lane];
#pragma unroll
        for (int j = 0; j < 64; ++j) {
            float ut = __uint_as_float(__builtin_amdgcn_readlane(__float_as_uint(uc), j));
            h = fmaf(Ab, h, Bb * ut);
        }
    }
    Hend[w][lane] = h;
    __syncthreads();

    // Phase 2: incoming state
    float AbL = expf((float)CHUNK * a);
    float H = 0.f;
    for (int v = 0; v < w; ++v)
        H = fmaf(H, AbL, Hend[v][lane]);

    // Phase 3: true scan, emit y
    h = H;
    float* Pw = &P[w][0][0];
    for (int t0 = 0; t0 < CHUNK; t0 += 64) {
        float uc = uw[t0 + lane];
#pragma unroll
        for (int half = 0; half < 2; ++half) {
#pragma unroll
            for (int j = 0; j < 32; ++j) {
                float ut = __uint_as_float(__builtin_amdgcn_readlane(__float_as_uint(uc), half * 32 + j));
                h = fmaf(Ab, h, Bb * ut);
                Pw[j * PSTRIDE + lane] = h * Cc;
            }
            __builtin_amdgcn_wave_barrier();
            int tl = lane >> 1, part = lane & 1;
            float s = 0.f;
#pragma unroll
            for (int q = 0; q < 8; ++q) {
                float4 pv = *(const float4*)&Pw[tl * PSTRIDE + part * 32 + q * 4];
                s += (pv.x + pv.y) + (pv.z + pv.w);
            }
            s += __shfl_xor(s, 1, 64);
            float ut2 = __shfl(uc, half * 32 + tl, 64);
            if (part == 0)
                yp[w * CHUNK + t0 + half * 32 + tl] = fmaf(Dd, ut2, s);
            __builtin_amdgcn_wave_barrier();
        }
    }
}

// ---------------- transpose + cast: yT fp32 [2][768][2048] -> yA bf16 [4096][768] ----------------
__global__ __launch_bounds__(256) void tcast_kernel(const float* __restrict__ yT,
                                                    ushort_t* __restrict__ yA) {
    __shared__ float T2[64 * 68];
    int t = threadIdx.x;
    int s0 = blockIdx.x * 64, d0 = blockIdx.y * 64, b = blockIdx.z;
    int dl = t >> 2, sq = (t & 3) * 16;
    const float* src = yT + ((size_t)b * D_MODEL + d0 + dl) * SEQ + s0 + sq;
#pragma unroll
    for (int q = 0; q < 4; ++q) {
        float4 v = *(const float4*)(src + q * 4);
        T2[(sq + q * 4 + 0) * 68 + dl] = v.x;
        T2[(sq + q * 4 + 1) * 68 + dl] = v.y;
        T2[(sq + q * 4 + 2) * 68 + dl] = v.z;
        T2[(sq + q * 4 + 3) * 68 + dl] = v.w;
    }
    __syncthreads();
    int sl = t >> 2, dseg = (t & 3) * 16;
    ushort_t* dst = yA + ((size_t)(b * SEQ + s0 + sl)) * D_MODEL + d0 + dseg;
#pragma unroll
    for (int q = 0; q < 4; ++q) {
        float4 v = *(const float4*)&T2[sl * 68 + dseg + q * 4];
        ushort4 o = make_ushort4(f2bf(v.x), f2bf(v.y), f2bf(v.z), f2bf(v.w));
        *(ushort4*)(dst + q * 4) = o;
    }
}

extern "C" void kernel_launch(void* const* d_in, const int* in_sizes, int n_in,
                              void* d_out, int out_size, void* d_ws, size_t ws_size,
                              hipStream_t stream) {
    const float* x        = (const float*)d_in[0];
    const float* ln_gamma = (const float*)d_in[1];
    const float* ln_beta  = (const float*)d_in[2];
    const float* W_in     = (const float*)d_in[3];
    const float* b_in     = (const float*)d_in[4];
    const float* log_A    = (const float*)d_in[5];
    const float* B_p      = (const float*)d_in[6];
    const float* C_p      = (const float*)d_in[7];
    const float* D_p      = (const float*)d_in[8];
    const float* log_dt   = (const float*)d_in[9];
    const float* W_out    = (const float*)d_in[10];
    const float* b_out    = (const float*)d_in[11];
    float* out = (float*)d_out;

    char* ws = (char*)d_ws;
    float*    uT    = (float*)(ws + 0);                       // 12582912 B
    float*    yT    = (float*)(ws + 12582912);                // 12582912 B
    ushort_t* xnb   = (ushort_t*)(ws + 25165824);             // 6291456 B (reused as yA)
    ushort_t* yA    = xnb;
    ushort_t* Winb  = (ushort_t*)(ws + 31457280);             // 1179648 B
    ushort_t* Woutb = (ushort_t*)(ws + 32636928);             // 1179648 B

    cast2_kernel<<<dim3(576, 2), 256, 0, stream>>>(W_in, W_out, Winb, Woutb);
    ln_kernel<<<dim3(M_TOTAL / 4), 256, 0, stream>>>(x, ln_gamma, ln_beta, xnb);
    gemm_in<<<dim3(M_TOTAL / 64, D_MODEL / 64), 256, 0, stream>>>(xnb, Winb, b_in, uT);
    scan_kernel<<<dim3(D_MODEL, BATCH), 512, 0, stream>>>(uT, log_A, B_p, C_p, D_p, log_dt, yT);
    tcast_kernel<<<dim3(SEQ / 64, D_MODEL / 64, BATCH), 256, 0, stream>>>(yT, yA);
    gemm_out<<<dim3(M_TOTAL / 64, D_MODEL / 64), 256, 0, stream>>>(yA, Woutb, b_out, x, out);
}

// Round 4
// 130.610 us; speedup vs baseline: 2.5832x; 1.2670x over previous
//
#include <hip/hip_runtime.h>
#include <math.h>

#define D_MODEL 768
#define D_STATE 64
#define BATCH   2
#define SEQ     2048
#define M_TOTAL (BATCH * SEQ)   // 4096

typedef unsigned short ushort_t;
typedef float f32x4 __attribute__((ext_vector_type(4)));
typedef __bf16 bf16x8 __attribute__((ext_vector_type(8)));

__device__ __forceinline__ ushort_t f2bf(float f) {
    unsigned u = __float_as_uint(f);
    u = (u + 0x7FFFu + ((u >> 16) & 1u)) >> 16;   // RNE
    return (ushort_t)u;
}

__device__ __forceinline__ void gload16(const void* g, void* shm) {
    __builtin_amdgcn_global_load_lds(
        (const __attribute__((address_space(1))) void*)g,
        (__attribute__((address_space(3))) void*)shm, 16, 0, 0);
}

// ---------------- weight cast fp32 -> bf16 ----------------
__global__ __launch_bounds__(256) void cast2_kernel(const float* __restrict__ w0,
                                                    const float* __restrict__ w1,
                                                    ushort_t* __restrict__ o0,
                                                    ushort_t* __restrict__ o1) {
    const float* src = blockIdx.y ? w1 : w0;
    ushort_t*    dst = blockIdx.y ? o1 : o0;
    int i = (blockIdx.x * 256 + threadIdx.x) * 4;
    float4 v = *(const float4*)(src + i);
    ushort4 o = make_ushort4(f2bf(v.x), f2bf(v.y), f2bf(v.z), f2bf(v.w));
    *(ushort4*)(dst + i) = o;
}

// ---------------- LayerNorm -> bf16 xn ----------------
__global__ __launch_bounds__(256) void ln_kernel(const float* __restrict__ x,
                                                 const float* __restrict__ gamma,
                                                 const float* __restrict__ beta,
                                                 ushort_t* __restrict__ xnb) {
    int row  = blockIdx.x * 4 + (threadIdx.x >> 6);
    int lane = threadIdx.x & 63;
    const float* xr = x + (size_t)row * D_MODEL;
    float4 v[3];
    v[0] = *(const float4*)(xr + lane * 4);
    v[1] = *(const float4*)(xr + 256 + lane * 4);
    v[2] = *(const float4*)(xr + 512 + lane * 4);
    float s = 0.f, ss = 0.f;
#pragma unroll
    for (int i = 0; i < 3; ++i) {
        s  += v[i].x + v[i].y + v[i].z + v[i].w;
        ss += v[i].x * v[i].x + v[i].y * v[i].y + v[i].z * v[i].z + v[i].w * v[i].w;
    }
#pragma unroll
    for (int off = 1; off < 64; off <<= 1) {
        s  += __shfl_xor(s, off, 64);
        ss += __shfl_xor(ss, off, 64);
    }
    float mean = s * (1.0f / 768.0f);
    float var  = ss * (1.0f / 768.0f) - mean * mean;
    float inv  = 1.0f / sqrtf(var + 1e-5f);
    ushort_t* xo = xnb + (size_t)row * D_MODEL;
#pragma unroll
    for (int i = 0; i < 3; ++i) {
        int c = i * 256 + lane * 4;
        float4 g  = *(const float4*)(gamma + c);
        float4 bb = *(const float4*)(beta + c);
        ushort4 o = make_ushort4(f2bf((v[i].x - mean) * inv * g.x + bb.x),
                                 f2bf((v[i].y - mean) * inv * g.y + bb.y),
                                 f2bf((v[i].z - mean) * inv * g.z + bb.z),
                                 f2bf((v[i].w - mean) * inv * g.w + bb.w));
        *(ushort4*)(xo + c) = o;
    }
}

// ---------------- gemm_in: u = xn @ W_in^T + b_in -> uTb bf16 [b][n][s] ----------------
__global__ __launch_bounds__(256) void gemm_in(const ushort_t* __restrict__ A,   // xn bf16 [4096][768]
                                               const ushort_t* __restrict__ B,   // W_in bf16 [768][768]
                                               const float* __restrict__ bias,
                                               ushort_t* __restrict__ uTb) {     // bf16 [2][768][2048]
    __shared__ __align__(16) char smem[64 * 68 * 4];
    float* T = (float*)smem;

    int tid = threadIdx.x;
    int w = tid >> 6, l = tid & 63;
    int bm = blockIdx.x * 64, bn = blockIdx.y * 64;
    int mq = (w & 1) * 32, nq = (w >> 1) * 32;

    int rowA = w * 8 + (l >> 3);
    int segx = ((l & 7) ^ (rowA & 7)) * 8;
    const ushort_t* gA0 = A + (size_t)(bm + rowA) * D_MODEL + segx;
    const ushort_t* gB0 = B + (size_t)(bn + rowA) * D_MODEL + segx;
    char* dA = smem + w * 1024;
    char* dB = smem + 8192 + w * 1024;

    float biasv[2];
#pragma unroll
    for (int nt = 0; nt < 2; ++nt)
        biasv[nt] = bias[bn + nq + nt * 16 + (l & 15)];

    f32x4 acc[2][2] = {};
    for (int k0 = 0; k0 < D_MODEL; k0 += 64) {
        gload16(gA0 + k0, dA);
        gload16(gA0 + k0 + (size_t)32 * D_MODEL, dA + 4096);
        gload16(gB0 + k0, dB);
        gload16(gB0 + k0 + (size_t)32 * D_MODEL, dB + 4096);
        __syncthreads();
#pragma unroll
        for (int kk = 0; kk < 2; ++kk) {
            bf16x8 af[2], bf[2];
#pragma unroll
            for (int mt = 0; mt < 2; ++mt) {
                int r = mq + mt * 16 + (l & 15);
                int sgi = (kk * 4 + (l >> 4)) ^ (r & 7);
                af[mt] = *(const bf16x8*)(smem + r * 128 + sgi * 16);
            }
#pragma unroll
            for (int nt = 0; nt < 2; ++nt) {
                int r = nq + nt * 16 + (l & 15);
                int sgi = (kk * 4 + (l >> 4)) ^ (r & 7);
                bf[nt] = *(const bf16x8*)(smem + 8192 + r * 128 + sgi * 16);
            }
#pragma unroll
            for (int mt = 0; mt < 2; ++mt)
#pragma unroll
                for (int nt = 0; nt < 2; ++nt)
                    acc[mt][nt] = __builtin_amdgcn_mfma_f32_16x16x32_bf16(af[mt], bf[nt], acc[mt][nt], 0, 0, 0);
        }
        __syncthreads();
    }
    // epilogue: LDS transpose -> uTb[b][n][s] bf16 coalesced
#pragma unroll
    for (int mt = 0; mt < 2; ++mt)
#pragma unroll
        for (int nt = 0; nt < 2; ++nt)
#pragma unroll
            for (int i = 0; i < 4; ++i) {
                int nl = nq + nt * 16 + (l & 15);
                int ml = mq + mt * 16 + (l >> 4) * 4 + i;
                T[nl * 68 + ml] = acc[mt][nt][i] + biasv[nt];
            }
    __syncthreads();
    int b = bm >> 11, sbase = bm & 2047;
    int n = tid >> 2, mseg = (tid & 3) * 16;
    ushort_t* dst = uTb + ((size_t)b * D_MODEL + bn + n) * SEQ + sbase + mseg;
#pragma unroll
    for (int q = 0; q < 4; ++q) {
        float4 v = *(const float4*)&T[n * 68 + mseg + q * 4];
        ushort4 o = make_ushort4(f2bf(v.x), f2bf(v.y), f2bf(v.z), f2bf(v.w));
        *(ushort4*)(dst + q * 4) = o;
    }
}

// ---------------- scan as blocked matmuls (SSD-style) ----------------
// One block (256 thr, 4 waves) per channel d. Chunk length 64; cols = (b,chunk)
// = 64 columns covering both batches. Per block:
//   precompute T[j][s] (Toeplitz, D folded), V[n][s], M[j][n]  (bf16, stride 72)
//   W  = V * U            (MFMA; fp32 -> LDS [col][n])
//   H scan: 32 serial fma per (b,n) lane; Hm[col][n] = state entering chunk
//   Y  = T * U + M * Hm   (MFMA; fp32 -> LDS [col][j], reusing W space)
//   write yT[b][d][s] coalesced.
#define OFF_U  0
#define OFF_V  9216
#define OFF_T  18432
#define OFF_M  27648
#define OFF_H  36864
#define OFF_W  46080          // 64*68*4 = 17408 (Kpart aliases this early)
#define OFF_SM 63488          // aArr,BbArr,CcArr,CBArr (4*256) + Kc (256)

__global__ __launch_bounds__(256) void scan_mm(const ushort_t* __restrict__ uTb,
                                               const float* __restrict__ log_A,
                                               const float* __restrict__ B_p,
                                               const float* __restrict__ C_p,
                                               const float* __restrict__ D_p,
                                               const float* __restrict__ log_dt,
                                               float* __restrict__ yT) {
    __shared__ __align__(16) char smem[65024];
    ushort_t* Up = (ushort_t*)(smem + OFF_U);
    ushort_t* Vp = (ushort_t*)(smem + OFF_V);
    ushort_t* Tp = (ushort_t*)(smem + OFF_T);
    ushort_t* Mp = (ushort_t*)(smem + OFF_M);
    ushort_t* Hp = (ushort_t*)(smem + OFF_H);
    float*    Wp = (float*)(smem + OFF_W);
    float*    Kp = (float*)(smem + OFF_W);   // alias: used before mm1 only
    float*    aArr  = (float*)(smem + OFF_SM);
    float*    BbArr = aArr + 64;
    float*    CcArr = aArr + 128;
    float*    CBArr = aArr + 192;
    float*    Kc    = aArr + 256;

    int d   = blockIdx.x;
    int tid = threadIdx.x;
    int w   = tid >> 6, l = tid & 63;

    // ---- per-state params ----
    if (tid < 64) {
        int n = tid;
        float dt = __expf(log_dt[d]);
        float a  = -dt * __expf(log_A[d * 64 + n]);
        float Bb = B_p[d * 64 + n] * dt;
        float Cc = C_p[d * 64 + n];
        aArr[n] = a; BbArr[n] = Bb; CcArr[n] = Cc; CBArr[n] = Cc * Bb;
    }
    __syncthreads();

    // ---- K(tau) partials ----
    {
        int tau = tid & 63, part = tid >> 6;
        float s = 0.f;
#pragma unroll
        for (int i = 0; i < 16; ++i) {
            int n = part * 16 + i;
            s += CBArr[n] * __expf((float)tau * aArr[n]);
        }
        Kp[part * 64 + tau] = s;
    }
    __syncthreads();
    if (tid < 64)
        Kc[tid] = Kp[tid] + Kp[64 + tid] + Kp[128 + tid] + Kp[192 + tid]
                + (tid == 0 ? D_p[d] : 0.f);
    __syncthreads();

    // ---- fill V, M, T + stage U ----
    {
        int r = tid >> 2, seg = (tid & 3) * 16;
        float a = aArr[r], Bb = BbArr[r];
#pragma unroll
        for (int i = 0; i < 16; ++i) {
            int s = seg + i;
            Vp[r * 72 + s] = f2bf(Bb * __expf((float)(63 - s) * a));
        }
#pragma unroll
        for (int i = 0; i < 16; ++i) {
            int n = seg + i;
            Mp[r * 72 + n] = f2bf(CcArr[n] * __expf((float)(r + 1) * aArr[n]));
        }
#pragma unroll
        for (int i = 0; i < 16; ++i) {
            int s = seg + i;
            Tp[r * 72 + s] = (s <= r) ? f2bf(Kc[r - s]) : (ushort_t)0;
        }
        // U[col][s] straight copy (col = b*32 + chunk)
        int col = r, bu = col >> 5, cu = col & 31;
        const ushort_t* usrc = uTb + ((size_t)bu * D_MODEL + d) * SEQ + cu * 64 + seg;
        *(uint4*)(Up + col * 72 + seg)     = *(const uint4*)(usrc);
        *(uint4*)(Up + col * 72 + seg + 8) = *(const uint4*)(usrc + 8);
    }
    __syncthreads();

    // ---- mm1: W[p=n][q=col] = sum_s V[p][s] U[q][s] ----
    {
        int p0 = w * 16;
        f32x4 acc1[4] = {};
#pragma unroll
        for (int kk = 0; kk < 2; ++kk) {
            int koff = kk * 32 + (l >> 4) * 8;
            bf16x8 af = *(const bf16x8*)(Vp + (p0 + (l & 15)) * 72 + koff);
#pragma unroll
            for (int qt = 0; qt < 4; ++qt) {
                bf16x8 bf = *(const bf16x8*)(Up + (qt * 16 + (l & 15)) * 72 + koff);
                acc1[qt] = __builtin_amdgcn_mfma_f32_16x16x32_bf16(af, bf, acc1[qt], 0, 0, 0);
            }
        }
#pragma unroll
        for (int qt = 0; qt < 4; ++qt)
#pragma unroll
            for (int i = 0; i < 4; ++i)
                Wp[(qt * 16 + (l & 15)) * 68 + p0 + (l >> 4) * 4 + i] = acc1[qt][i];
    }
    __syncthreads();

    // ---- serial chunk scan (the only sequential part: 32 fma per (b,n)) ----
    if (tid < 128) {
        int b2 = tid >> 6, n = tid & 63;
        float Ab64 = __expf(64.f * aArr[n]);
        float H = 0.f;
#pragma unroll
        for (int c = 0; c < 32; ++c) {
            int col = b2 * 32 + c;
            Hp[col * 72 + n] = f2bf(H);
            H = fmaf(Ab64, H, Wp[col * 68 + n]);
        }
    }
    __syncthreads();

    // ---- mm2/3: Y[j][col] = sum_s T[j][s]U[col][s] + sum_n M[j][n]H[col][n] ----
    {
        int j0 = w * 16;
        f32x4 accY[4] = {};
#pragma unroll
        for (int kk = 0; kk < 2; ++kk) {
            int koff = kk * 32 + (l >> 4) * 8;
            bf16x8 at = *(const bf16x8*)(Tp + (j0 + (l & 15)) * 72 + koff);
            bf16x8 am = *(const bf16x8*)(Mp + (j0 + (l & 15)) * 72 + koff);
#pragma unroll
            for (int qt = 0; qt < 4; ++qt) {
                bf16x8 bu = *(const bf16x8*)(Up + (qt * 16 + (l & 15)) * 72 + koff);
                bf16x8 bh = *(const bf16x8*)(Hp + (qt * 16 + (l & 15)) * 72 + koff);
                accY[qt] = __builtin_amdgcn_mfma_f32_16x16x32_bf16(at, bu, accY[qt], 0, 0, 0);
                accY[qt] = __builtin_amdgcn_mfma_f32_16x16x32_bf16(am, bh, accY[qt], 0, 0, 0);
            }
        }
#pragma unroll
        for (int qt = 0; qt < 4; ++qt)
#pragma unroll
            for (int i = 0; i < 4; ++i)
                Wp[(qt * 16 + (l & 15)) * 68 + j0 + (l >> 4) * 4 + i] = accY[qt][i];
    }
    __syncthreads();

    // ---- write yT[b][d][s] coalesced ----
    {
        int col = tid >> 2, jseg = (tid & 3) * 16;
        int b3 = col >> 5, c3 = col & 31;
        float* dst = yT + ((size_t)b3 * D_MODEL + d) * SEQ + c3 * 64 + jseg;
#pragma unroll
        for (int q = 0; q < 4; ++q)
            *(float4*)(dst + q * 4) = *(const float4*)(Wp + col * 68 + jseg + q * 4);
    }
}

// ---------------- transpose + cast: yT fp32 [2][768][2048] -> yA bf16 [4096][768] ----------------
__global__ __launch_bounds__(256) void tcast_kernel(const float* __restrict__ yT,
                                                    ushort_t* __restrict__ yA) {
    __shared__ float T2[64 * 68];
    int t = threadIdx.x;
    int s0 = blockIdx.x * 64, d0 = blockIdx.y * 64, b = blockIdx.z;
    int dl = t >> 2, sq = (t & 3) * 16;
    const float* src = yT + ((size_t)b * D_MODEL + d0 + dl) * SEQ + s0 + sq;
#pragma unroll
    for (int q = 0; q < 4; ++q) {
        float4 v = *(const float4*)(src + q * 4);
        T2[(sq + q * 4 + 0) * 68 + dl] = v.x;
        T2[(sq + q * 4 + 1) * 68 + dl] = v.y;
        T2[(sq + q * 4 + 2) * 68 + dl] = v.z;
        T2[(sq + q * 4 + 3) * 68 + dl] = v.w;
    }
    __syncthreads();
    int sl = t >> 2, dseg = (t & 3) * 16;
    ushort_t* dst = yA + ((size_t)(b * SEQ + s0 + sl)) * D_MODEL + d0 + dseg;
#pragma unroll
    for (int q = 0; q < 4; ++q) {
        float4 v = *(const float4*)&T2[sl * 68 + dseg + q * 4];
        ushort4 o = make_ushort4(f2bf(v.x), f2bf(v.y), f2bf(v.z), f2bf(v.w));
        *(ushort4*)(dst + q * 4) = o;
    }
}

// ---------------- gemm_out: out = y @ W_out^T + b_out + resid ----------------
__global__ __launch_bounds__(256) void gemm_out(const ushort_t* __restrict__ A,   // y bf16 [4096][768]
                                                const ushort_t* __restrict__ B,   // W_out bf16 [768][768]
                                                const float* __restrict__ bias,
                                                const float* __restrict__ resid,
                                                float* __restrict__ out) {
    __shared__ __align__(16) char smem[16384];
    int tid = threadIdx.x;
    int w = tid >> 6, l = tid & 63;
    int bm = blockIdx.x * 64, bn = blockIdx.y * 64;
    int mq = (w & 1) * 32, nq = (w >> 1) * 32;

    int rowA = w * 8 + (l >> 3);
    int segx = ((l & 7) ^ (rowA & 7)) * 8;
    const ushort_t* gA0 = A + (size_t)(bm + rowA) * D_MODEL + segx;
    const ushort_t* gB0 = B + (size_t)(bn + rowA) * D_MODEL + segx;
    char* dA = smem + w * 1024;
    char* dB = smem + 8192 + w * 1024;

    float biasv[2];
#pragma unroll
    for (int nt = 0; nt < 2; ++nt)
        biasv[nt] = bias[bn + nq + nt * 16 + (l & 15)];

    f32x4 acc[2][2] = {};
    for (int k0 = 0; k0 < D_MODEL; k0 += 64) {
        gload16(gA0 + k0, dA);
        gload16(gA0 + k0 + (size_t)32 * D_MODEL, dA + 4096);
        gload16(gB0 + k0, dB);
        gload16(gB0 + k0 + (size_t)32 * D_MODEL, dB + 4096);
        __syncthreads();
#pragma unroll
        for (int kk = 0; kk < 2; ++kk) {
            bf16x8 af[2], bf[2];
#pragma unroll
            for (int mt = 0; mt < 2; ++mt) {
                int r = mq + mt * 16 + (l & 15);
                int sgi = (kk * 4 + (l >> 4)) ^ (r & 7);
                af[mt] = *(const bf16x8*)(smem + r * 128 + sgi * 16);
            }
#pragma unroll
            for (int nt = 0; nt < 2; ++nt) {
                int r = nq + nt * 16 + (l & 15);
                int sgi = (kk * 4 + (l >> 4)) ^ (r & 7);
                bf[nt] = *(const bf16x8*)(smem + 8192 + r * 128 + sgi * 16);
            }
#pragma unroll
            for (int mt = 0; mt < 2; ++mt)
#pragma unroll
                for (int nt = 0; nt < 2; ++nt)
                    acc[mt][nt] = __builtin_amdgcn_mfma_f32_16x16x32_bf16(af[mt], bf[nt], acc[mt][nt], 0, 0, 0);
        }
        __syncthreads();
    }
#pragma unroll
    for (int mt = 0; mt < 2; ++mt)
#pragma unroll
        for (int i = 0; i < 4; ++i) {
            int m = bm + mq + mt * 16 + (l >> 4) * 4 + i;
            const float* rp = resid + (size_t)m * D_MODEL + bn;
            float* op = out + (size_t)m * D_MODEL + bn;
#pragma unroll
            for (int nt = 0; nt < 2; ++nt) {
                int nl = nq + nt * 16 + (l & 15);
                op[nl] = acc[mt][nt][i] + biasv[nt] + rp[nl];
            }
        }
}

extern "C" void kernel_launch(void* const* d_in, const int* in_sizes, int n_in,
                              void* d_out, int out_size, void* d_ws, size_t ws_size,
                              hipStream_t stream) {
    const float* x        = (const float*)d_in[0];
    const float* ln_gamma = (const float*)d_in[1];
    const float* ln_beta  = (const float*)d_in[2];
    const float* W_in     = (const float*)d_in[3];
    const float* b_in     = (const float*)d_in[4];
    const float* log_A    = (const float*)d_in[5];
    const float* B_p      = (const float*)d_in[6];
    const float* C_p      = (const float*)d_in[7];
    const float* D_p      = (const float*)d_in[8];
    const float* log_dt   = (const float*)d_in[9];
    const float* W_out    = (const float*)d_in[10];
    const float* b_out    = (const float*)d_in[11];
    float* out = (float*)d_out;

    char* ws = (char*)d_ws;
    ushort_t* uTb   = (ushort_t*)(ws + 0);                    // 6291456 B
    float*    yT    = (float*)(ws + 6291456);                 // 12582912 B
    ushort_t* xnb   = (ushort_t*)(ws + 18874368);             // 6291456 B (reused as yA)
    ushort_t* yA    = xnb;
    ushort_t* Winb  = (ushort_t*)(ws + 25165824);             // 1179648 B
    ushort_t* Woutb = (ushort_t*)(ws + 26345472);             // 1179648 B

    cast2_kernel<<<dim3(576, 2), 256, 0, stream>>>(W_in, W_out, Winb, Woutb);
    ln_kernel<<<dim3(M_TOTAL / 4), 256, 0, stream>>>(x, ln_gamma, ln_beta, xnb);
    gemm_in<<<dim3(M_TOTAL / 64, D_MODEL / 64), 256, 0, stream>>>(xnb, Winb, b_in, uTb);
    scan_mm<<<dim3(D_MODEL), 256, 0, stream>>>(uTb, log_A, B_p, C_p, D_p, log_dt, yT);
    tcast_kernel<<<dim3(SEQ / 64, D_MODEL / 64, BATCH), 256, 0, stream>>>(yT, yA);
    gemm_out<<<dim3(M_TOTAL / 64, D_MODEL / 64), 256, 0, stream>>>(yA, Woutb, b_out, x, out);
}

// Round 5
// 129.159 us; speedup vs baseline: 2.6122x; 1.0112x over previous
//
#include <hip/hip_runtime.h>
#include <math.h>

#define D_MODEL 768
#define D_STATE 64
#define BATCH   2
#define SEQ     2048
#define M_TOTAL (BATCH * SEQ)   // 4096

typedef unsigned short ushort_t;
typedef float f32x4 __attribute__((ext_vector_type(4)));
typedef __bf16 bf16x8 __attribute__((ext_vector_type(8)));

__device__ __forceinline__ ushort_t f2bf(float f) {
    unsigned u = __float_as_uint(f);
    u = (u + 0x7FFFu + ((u >> 16) & 1u)) >> 16;   // RNE
    return (ushort_t)u;
}

__device__ __forceinline__ void gload16(const void* g, void* shm) {
    __builtin_amdgcn_global_load_lds(
        (const __attribute__((address_space(1))) void*)g,
        (__attribute__((address_space(3))) void*)shm, 16, 0, 0);
}

// ---------------- fused pre-kernel: LayerNorm->bf16 (blocks 0..1023) + weight casts (blocks 1024..2175) ----------------
__global__ __launch_bounds__(256) void pre_kernel(const float* __restrict__ x,
                                                  const float* __restrict__ gamma,
                                                  const float* __restrict__ beta,
                                                  ushort_t* __restrict__ xnb,
                                                  const float* __restrict__ W_in,
                                                  const float* __restrict__ W_out,
                                                  ushort_t* __restrict__ Winb,
                                                  ushort_t* __restrict__ Woutb) {
    int bx = blockIdx.x;
    if (bx >= 1024) {
        int b2 = bx - 1024;                    // 0..1151
        const float* src = (b2 < 576) ? W_in : W_out;
        ushort_t*    dst = (b2 < 576) ? Winb : Woutb;
        int blk = (b2 < 576) ? b2 : b2 - 576;
        int i = (blk * 256 + threadIdx.x) * 4;
        float4 v = *(const float4*)(src + i);
        ushort4 o = make_ushort4(f2bf(v.x), f2bf(v.y), f2bf(v.z), f2bf(v.w));
        *(ushort4*)(dst + i) = o;
        return;
    }
    int row  = bx * 4 + (threadIdx.x >> 6);
    int lane = threadIdx.x & 63;
    const float* xr = x + (size_t)row * D_MODEL;
    float4 v[3];
    v[0] = *(const float4*)(xr + lane * 4);
    v[1] = *(const float4*)(xr + 256 + lane * 4);
    v[2] = *(const float4*)(xr + 512 + lane * 4);
    float s = 0.f, ss = 0.f;
#pragma unroll
    for (int i = 0; i < 3; ++i) {
        s  += v[i].x + v[i].y + v[i].z + v[i].w;
        ss += v[i].x * v[i].x + v[i].y * v[i].y + v[i].z * v[i].z + v[i].w * v[i].w;
    }
#pragma unroll
    for (int off = 1; off < 64; off <<= 1) {
        s  += __shfl_xor(s, off, 64);
        ss += __shfl_xor(ss, off, 64);
    }
    float mean = s * (1.0f / 768.0f);
    float var  = ss * (1.0f / 768.0f) - mean * mean;
    float inv  = 1.0f / sqrtf(var + 1e-5f);
    ushort_t* xo = xnb + (size_t)row * D_MODEL;
#pragma unroll
    for (int i = 0; i < 3; ++i) {
        int c = i * 256 + lane * 4;
        float4 g  = *(const float4*)(gamma + c);
        float4 bb = *(const float4*)(beta + c);
        ushort4 o = make_ushort4(f2bf((v[i].x - mean) * inv * g.x + bb.x),
                                 f2bf((v[i].y - mean) * inv * g.y + bb.y),
                                 f2bf((v[i].z - mean) * inv * g.z + bb.z),
                                 f2bf((v[i].w - mean) * inv * g.w + bb.w));
        *(ushort4*)(xo + c) = o;
    }
}

// ---------------- bf16 MFMA GEMM, 64x64 tile, BK=128 ----------------
// LDS rows = 256 B (128 bf16) = 16 segs of 16B; seg sg of row r stored at
// slot (sg ^ (r&7)) -> ds_read_b128 fragment reads are 2-way max (free),
// global_load_lds staging keeps lane-contiguous LDS dst. 6 K-iterations.

// gemm_in: u = xn @ W_in^T + b_in -> uTb bf16 [b][n][s] (LDS-transposed epilogue)
__global__ __launch_bounds__(256) void gemm_in(const ushort_t* __restrict__ A,   // xn bf16 [4096][768]
                                               const ushort_t* __restrict__ B,   // W_in bf16 [768][768]
                                               const float* __restrict__ bias,
                                               ushort_t* __restrict__ uTb) {     // bf16 [2][768][2048]
    __shared__ __align__(16) char smem[32768];
    float* T = (float*)smem;                 // epilogue alias (17408 B)

    int tid = threadIdx.x;
    int w = tid >> 6, l = tid & 63;
    int bm = blockIdx.x * 64, bn = blockIdx.y * 64;
    int mq = (w & 1) * 32, nq = (w >> 1) * 32;

    int rowq = l >> 4;         // 0..3
    int segq = l & 15;         // 0..15

    float biasv[2];
#pragma unroll
    for (int nt = 0; nt < 2; ++nt)
        biasv[nt] = bias[bn + nq + nt * 16 + (l & 15)];

    f32x4 acc[2][2] = {};
    for (int k0 = 0; k0 < D_MODEL; k0 += 128) {
#pragma unroll
        for (int q = 0; q < 4; ++q) {
            int row = w * 16 + q * 4 + rowq;
            int col = k0 + ((segq ^ (row & 7)) * 8);
            gload16(A + (size_t)(bm + row) * D_MODEL + col, smem + w * 4096 + q * 1024);
            gload16(B + (size_t)(bn + row) * D_MODEL + col, smem + 16384 + w * 4096 + q * 1024);
        }
        __syncthreads();
#pragma unroll
        for (int kk = 0; kk < 4; ++kk) {
            int sgb = kk * 4 + (l >> 4);
            bf16x8 af[2], bf[2];
#pragma unroll
            for (int mt = 0; mt < 2; ++mt) {
                int r = mq + mt * 16 + (l & 15);
                af[mt] = *(const bf16x8*)(smem + r * 256 + ((sgb ^ (r & 7)) * 16));
            }
#pragma unroll
            for (int nt = 0; nt < 2; ++nt) {
                int r = nq + nt * 16 + (l & 15);
                bf[nt] = *(const bf16x8*)(smem + 16384 + r * 256 + ((sgb ^ (r & 7)) * 16));
            }
#pragma unroll
            for (int mt = 0; mt < 2; ++mt)
#pragma unroll
                for (int nt = 0; nt < 2; ++nt)
                    acc[mt][nt] = __builtin_amdgcn_mfma_f32_16x16x32_bf16(af[mt], bf[nt], acc[mt][nt], 0, 0, 0);
        }
        __syncthreads();
    }
    // epilogue: LDS transpose -> uTb[b][n][s] bf16 coalesced
#pragma unroll
    for (int mt = 0; mt < 2; ++mt)
#pragma unroll
        for (int nt = 0; nt < 2; ++nt)
#pragma unroll
            for (int i = 0; i < 4; ++i) {
                int nl = nq + nt * 16 + (l & 15);
                int ml = mq + mt * 16 + (l >> 4) * 4 + i;
                T[nl * 68 + ml] = acc[mt][nt][i] + biasv[nt];
            }
    __syncthreads();
    int b = bm >> 11, sbase = bm & 2047;
    int n = tid >> 2, mseg = (tid & 3) * 16;
    ushort_t* dst = uTb + ((size_t)b * D_MODEL + bn + n) * SEQ + sbase + mseg;
#pragma unroll
    for (int q = 0; q < 4; ++q) {
        float4 v = *(const float4*)&T[n * 68 + mseg + q * 4];
        ushort4 o = make_ushort4(f2bf(v.x), f2bf(v.y), f2bf(v.z), f2bf(v.w));
        *(ushort4*)(dst + q * 4) = o;
    }
}

// gemm_out: out = y @ W_out^T + b_out + resid, natural [m][n] fp32 store
__global__ __launch_bounds__(256) void gemm_out(const ushort_t* __restrict__ A,   // y bf16 [4096][768]
                                                const ushort_t* __restrict__ B,   // W_out bf16 [768][768]
                                                const float* __restrict__ bias,
                                                const float* __restrict__ resid,
                                                float* __restrict__ out) {
    __shared__ __align__(16) char smem[32768];
    int tid = threadIdx.x;
    int w = tid >> 6, l = tid & 63;
    int bm = blockIdx.x * 64, bn = blockIdx.y * 64;
    int mq = (w & 1) * 32, nq = (w >> 1) * 32;

    int rowq = l >> 4;
    int segq = l & 15;

    float biasv[2];
#pragma unroll
    for (int nt = 0; nt < 2; ++nt)
        biasv[nt] = bias[bn + nq + nt * 16 + (l & 15)];

    f32x4 acc[2][2] = {};
    for (int k0 = 0; k0 < D_MODEL; k0 += 128) {
#pragma unroll
        for (int q = 0; q < 4; ++q) {
            int row = w * 16 + q * 4 + rowq;
            int col = k0 + ((segq ^ (row & 7)) * 8);
            gload16(A + (size_t)(bm + row) * D_MODEL + col, smem + w * 4096 + q * 1024);
            gload16(B + (size_t)(bn + row) * D_MODEL + col, smem + 16384 + w * 4096 + q * 1024);
        }
        __syncthreads();
#pragma unroll
        for (int kk = 0; kk < 4; ++kk) {
            int sgb = kk * 4 + (l >> 4);
            bf16x8 af[2], bf[2];
#pragma unroll
            for (int mt = 0; mt < 2; ++mt) {
                int r = mq + mt * 16 + (l & 15);
                af[mt] = *(const bf16x8*)(smem + r * 256 + ((sgb ^ (r & 7)) * 16));
            }
#pragma unroll
            for (int nt = 0; nt < 2; ++nt) {
                int r = nq + nt * 16 + (l & 15);
                bf[nt] = *(const bf16x8*)(smem + 16384 + r * 256 + ((sgb ^ (r & 7)) * 16));
            }
#pragma unroll
            for (int mt = 0; mt < 2; ++mt)
#pragma unroll
                for (int nt = 0; nt < 2; ++nt)
                    acc[mt][nt] = __builtin_amdgcn_mfma_f32_16x16x32_bf16(af[mt], bf[nt], acc[mt][nt], 0, 0, 0);
        }
        __syncthreads();
    }
#pragma unroll
    for (int mt = 0; mt < 2; ++mt)
#pragma unroll
        for (int i = 0; i < 4; ++i) {
            int m = bm + mq + mt * 16 + (l >> 4) * 4 + i;
            const float* rp = resid + (size_t)m * D_MODEL + bn;
            float* op = out + (size_t)m * D_MODEL + bn;
#pragma unroll
            for (int nt = 0; nt < 2; ++nt) {
                int nl = nq + nt * 16 + (l & 15);
                op[nl] = acc[mt][nt][i] + biasv[nt] + rp[nl];
            }
        }
}

// ---------------- scan as blocked matmuls (SSD-style) ----------------
#define OFF_U  0
#define OFF_V  9216
#define OFF_T  18432
#define OFF_M  27648
#define OFF_H  36864
#define OFF_W  46080
#define OFF_SM 63488

__global__ __launch_bounds__(256) void scan_mm(const ushort_t* __restrict__ uTb,
                                               const float* __restrict__ log_A,
                                               const float* __restrict__ B_p,
                                               const float* __restrict__ C_p,
                                               const float* __restrict__ D_p,
                                               const float* __restrict__ log_dt,
                                               float* __restrict__ yT) {
    __shared__ __align__(16) char smem[65024];
    ushort_t* Up = (ushort_t*)(smem + OFF_U);
    ushort_t* Vp = (ushort_t*)(smem + OFF_V);
    ushort_t* Tp = (ushort_t*)(smem + OFF_T);
    ushort_t* Mp = (ushort_t*)(smem + OFF_M);
    ushort_t* Hp = (ushort_t*)(smem + OFF_H);
    float*    Wp = (float*)(smem + OFF_W);
    float*    Kp = (float*)(smem + OFF_W);
    float*    aArr  = (float*)(smem + OFF_SM);
    float*    BbArr = aArr + 64;
    float*    CcArr = aArr + 128;
    float*    CBArr = aArr + 192;
    float*    Kc    = aArr + 256;

    int d   = blockIdx.x;
    int tid = threadIdx.x;
    int w   = tid >> 6, l = tid & 63;

    if (tid < 64) {
        int n = tid;
        float dt = __expf(log_dt[d]);
        float a  = -dt * __expf(log_A[d * 64 + n]);
        float Bb = B_p[d * 64 + n] * dt;
        float Cc = C_p[d * 64 + n];
        aArr[n] = a; BbArr[n] = Bb; CcArr[n] = Cc; CBArr[n] = Cc * Bb;
    }
    __syncthreads();

    {
        int tau = tid & 63, part = tid >> 6;
        float s = 0.f;
#pragma unroll
        for (int i = 0; i < 16; ++i) {
            int n = part * 16 + i;
            s += CBArr[n] * __expf((float)tau * aArr[n]);
        }
        Kp[part * 64 + tau] = s;
    }
    __syncthreads();
    if (tid < 64)
        Kc[tid] = Kp[tid] + Kp[64 + tid] + Kp[128 + tid] + Kp[192 + tid]
                + (tid == 0 ? D_p[d] : 0.f);
    __syncthreads();

    {
        int r = tid >> 2, seg = (tid & 3) * 16;
        float a = aArr[r], Bb = BbArr[r];
#pragma unroll
        for (int i = 0; i < 16; ++i) {
            int s = seg + i;
            Vp[r * 72 + s] = f2bf(Bb * __expf((float)(63 - s) * a));
        }
#pragma unroll
        for (int i = 0; i < 16; ++i) {
            int n = seg + i;
            Mp[r * 72 + n] = f2bf(CcArr[n] * __expf((float)(r + 1) * aArr[n]));
        }
#pragma unroll
        for (int i = 0; i < 16; ++i) {
            int s = seg + i;
            Tp[r * 72 + s] = (s <= r) ? f2bf(Kc[r - s]) : (ushort_t)0;
        }
        int col = r, bu = col >> 5, cu = col & 31;
        const ushort_t* usrc = uTb + ((size_t)bu * D_MODEL + d) * SEQ + cu * 64 + seg;
        *(uint4*)(Up + col * 72 + seg)     = *(const uint4*)(usrc);
        *(uint4*)(Up + col * 72 + seg + 8) = *(const uint4*)(usrc + 8);
    }
    __syncthreads();

    {
        int p0 = w * 16;
        f32x4 acc1[4] = {};
#pragma unroll
        for (int kk = 0; kk < 2; ++kk) {
            int koff = kk * 32 + (l >> 4) * 8;
            bf16x8 af = *(const bf16x8*)(Vp + (p0 + (l & 15)) * 72 + koff);
#pragma unroll
            for (int qt = 0; qt < 4; ++qt) {
                bf16x8 bf = *(const bf16x8*)(Up + (qt * 16 + (l & 15)) * 72 + koff);
                acc1[qt] = __builtin_amdgcn_mfma_f32_16x16x32_bf16(af, bf, acc1[qt], 0, 0, 0);
            }
        }
#pragma unroll
        for (int qt = 0; qt < 4; ++qt)
#pragma unroll
            for (int i = 0; i < 4; ++i)
                Wp[(qt * 16 + (l & 15)) * 68 + p0 + (l >> 4) * 4 + i] = acc1[qt][i];
    }
    __syncthreads();

    if (tid < 128) {
        int b2 = tid >> 6, n = tid & 63;
        float Ab64 = __expf(64.f * aArr[n]);
        float H = 0.f;
#pragma unroll
        for (int c = 0; c < 32; ++c) {
            int col = b2 * 32 + c;
            Hp[col * 72 + n] = f2bf(H);
            H = fmaf(Ab64, H, Wp[col * 68 + n]);
        }
    }
    __syncthreads();

    {
        int j0 = w * 16;
        f32x4 accY[4] = {};
#pragma unroll
        for (int kk = 0; kk < 2; ++kk) {
            int koff = kk * 32 + (l >> 4) * 8;
            bf16x8 at = *(const bf16x8*)(Tp + (j0 + (l & 15)) * 72 + koff);
            bf16x8 am = *(const bf16x8*)(Mp + (j0 + (l & 15)) * 72 + koff);
#pragma unroll
            for (int qt = 0; qt < 4; ++qt) {
                bf16x8 bu = *(const bf16x8*)(Up + (qt * 16 + (l & 15)) * 72 + koff);
                bf16x8 bh = *(const bf16x8*)(Hp + (qt * 16 + (l & 15)) * 72 + koff);
                accY[qt] = __builtin_amdgcn_mfma_f32_16x16x32_bf16(at, bu, accY[qt], 0, 0, 0);
                accY[qt] = __builtin_amdgcn_mfma_f32_16x16x32_bf16(am, bh, accY[qt], 0, 0, 0);
            }
        }
#pragma unroll
        for (int qt = 0; qt < 4; ++qt)
#pragma unroll
            for (int i = 0; i < 4; ++i)
                Wp[(qt * 16 + (l & 15)) * 68 + j0 + (l >> 4) * 4 + i] = accY[qt][i];
    }
    __syncthreads();

    {
        int col = tid >> 2, jseg = (tid & 3) * 16;
        int b3 = col >> 5, c3 = col & 31;
        float* dst = yT + ((size_t)b3 * D_MODEL + d) * SEQ + c3 * 64 + jseg;
#pragma unroll
        for (int q = 0; q < 4; ++q)
            *(float4*)(dst + q * 4) = *(const float4*)(Wp + col * 68 + jseg + q * 4);
    }
}

// ---------------- transpose + cast: yT fp32 [2][768][2048] -> yA bf16 [4096][768] ----------------
__global__ __launch_bounds__(256) void tcast_kernel(const float* __restrict__ yT,
                                                    ushort_t* __restrict__ yA) {
    __shared__ float T2[64 * 68];
    int t = threadIdx.x;
    int s0 = blockIdx.x * 64, d0 = blockIdx.y * 64, b = blockIdx.z;
    int dl = t >> 2, sq = (t & 3) * 16;
    const float* src = yT + ((size_t)b * D_MODEL + d0 + dl) * SEQ + s0 + sq;
#pragma unroll
    for (int q = 0; q < 4; ++q) {
        float4 v = *(const float4*)(src + q * 4);
        T2[(sq + q * 4 + 0) * 68 + dl] = v.x;
        T2[(sq + q * 4 + 1) * 68 + dl] = v.y;
        T2[(sq + q * 4 + 2) * 68 + dl] = v.z;
        T2[(sq + q * 4 + 3) * 68 + dl] = v.w;
    }
    __syncthreads();
    int sl = t >> 2, dseg = (t & 3) * 16;
    ushort_t* dst = yA + ((size_t)(b * SEQ + s0 + sl)) * D_MODEL + d0 + dseg;
#pragma unroll
    for (int q = 0; q < 4; ++q) {
        float4 v = *(const float4*)&T2[sl * 68 + dseg + q * 4];
        ushort4 o = make_ushort4(f2bf(v.x), f2bf(v.y), f2bf(v.z), f2bf(v.w));
        *(ushort4*)(dst + q * 4) = o;
    }
}

extern "C" void kernel_launch(void* const* d_in, const int* in_sizes, int n_in,
                              void* d_out, int out_size, void* d_ws, size_t ws_size,
                              hipStream_t stream) {
    const float* x        = (const float*)d_in[0];
    const float* ln_gamma = (const float*)d_in[1];
    const float* ln_beta  = (const float*)d_in[2];
    const float* W_in     = (const float*)d_in[3];
    const float* b_in     = (const float*)d_in[4];
    const float* log_A    = (const float*)d_in[5];
    const float* B_p      = (const float*)d_in[6];
    const float* C_p      = (const float*)d_in[7];
    const float* D_p      = (const float*)d_in[8];
    const float* log_dt   = (const float*)d_in[9];
    const float* W_out    = (const float*)d_in[10];
    const float* b_out    = (const float*)d_in[11];
    float* out = (float*)d_out;

    char* ws = (char*)d_ws;
    ushort_t* uTb   = (ushort_t*)(ws + 0);                    // 6291456 B
    float*    yT    = (float*)(ws + 6291456);                 // 12582912 B
    ushort_t* xnb   = (ushort_t*)(ws + 18874368);             // 6291456 B (reused as yA)
    ushort_t* yA    = xnb;
    ushort_t* Winb  = (ushort_t*)(ws + 25165824);             // 1179648 B
    ushort_t* Woutb = (ushort_t*)(ws + 26345472);             // 1179648 B

    pre_kernel<<<dim3(1024 + 1152), 256, 0, stream>>>(x, ln_gamma, ln_beta, xnb,
                                                      W_in, W_out, Winb, Woutb);
    gemm_in<<<dim3(M_TOTAL / 64, D_MODEL / 64), 256, 0, stream>>>(xnb, Winb, b_in, uTb);
    scan_mm<<<dim3(D_MODEL), 256, 0, stream>>>(uTb, log_A, B_p, C_p, D_p, log_dt, yT);
    tcast_kernel<<<dim3(SEQ / 64, D_MODEL / 64, BATCH), 256, 0, stream>>>(yT, yA);
    gemm_out<<<dim3(M_TOTAL / 64, D_MODEL / 64), 256, 0, stream>>>(yA, Woutb, b_out, x, out);
}